// Round 1
// baseline (286.200 us; speedup 1.0000x reference)
//
#include <hip/hip_runtime.h>
#include <math.h>

#define NSIG 32768
#define KD   512
#define ED   64
#define SP   5

// ---------------- kernel A: DtD = Dt @ D + eps*I  (f64) ----------------
__global__ __launch_bounds__(256) void k_dtd(const float* __restrict__ D,
                                             double* __restrict__ DtD) {
  int flat = blockIdx.x * 256 + threadIdx.x;   // 0..262143
  int i = flat >> 9, j = flat & 511;
  double acc = 0.0;
  #pragma unroll
  for (int e = 0; e < ED; ++e)
    acc += (double)D[e * KD + i] * (double)D[e * KD + j];
  if (i == j) acc += 1e-10;
  DtD[flat] = acc;
}

// ---------------- zero the coefficients output region ----------------
__global__ __launch_bounds__(256) void k_zero(float* __restrict__ p, size_t count) {
  size_t i = (size_t)blockIdx.x * 256 + threadIdx.x;
  size_t stride = (size_t)gridDim.x * 256;
  for (; i < count; i += stride) p[i] = 0.0f;
}

// ---------------- kernel B: corr0 = Dt @ Z  (f64 accumulate) ----------------
// tile: 512 atoms x 16 signals per block; thread: 8 atoms x 4 signals
__global__ __launch_bounds__(256) void k_corr0(const float* __restrict__ z,
                                               const float* __restrict__ D,
                                               double* __restrict__ corr0, int n0) {
  int tid = threadIdx.x;
  int g  = tid & 63;        // atom group: atoms g*8 .. g*8+7
  int sg = tid >> 6;        // 0..3 signal subgroup
  int srel = blockIdx.x * 16 + sg * 4;      // chunk-relative signal base
  int n = n0 + srel;
  int b = n >> 10, p = n & 1023;
  const float* zp = z + (size_t)b * 65536 + p;   // + e*1024
  const float* dp = D + g * 8;                   // + e*512
  double acc[4][8];
  #pragma unroll
  for (int s = 0; s < 4; ++s)
    #pragma unroll
    for (int a = 0; a < 8; ++a) acc[s][a] = 0.0;
  for (int e = 0; e < ED; ++e) {
    const float4 zv = *(const float4*)(zp + (size_t)e * 1024);
    const float4 d0 = *(const float4*)(dp + (size_t)e * KD);
    const float4 d1 = *(const float4*)(dp + (size_t)e * KD + 4);
    double dz[4] = {(double)zv.x, (double)zv.y, (double)zv.z, (double)zv.w};
    double dd[8] = {(double)d0.x, (double)d0.y, (double)d0.z, (double)d0.w,
                    (double)d1.x, (double)d1.y, (double)d1.z, (double)d1.w};
    #pragma unroll
    for (int s = 0; s < 4; ++s)
      #pragma unroll
      for (int a = 0; a < 8; ++a) acc[s][a] += dz[s] * dd[a];
  }
  #pragma unroll
  for (int s = 0; s < 4; ++s) {
    double* o = corr0 + (size_t)(srel + s) * KD + g * 8;
    #pragma unroll
    for (int a = 0; a < 8; ++a) o[a] = acc[s][a];
  }
}

// ---------------- kernel C: per-signal OMP (wave per signal) ----------------
template <int K>
__device__ __forceinline__ void omp_iter(const double* __restrict__ c0row,
                                         const double* __restrict__ DtD,
                                         double (&c0)[8], unsigned& amask,
                                         int (&idx)[SP], double (&cc)[SP],
                                         double (&G)[SP][SP], double (&c0sel)[SP],
                                         int lane) {
  // ----- masked corr scan over this lane's 8 atoms -----
  double vb = -INFINITY;
  int ab = 0x7FFFFFFF;
  #pragma unroll
  for (int j = 0; j < 8; ++j) {
    int a = (j << 6) + lane;
    double v = c0[j];
    #pragma unroll
    for (int m = 0; m < K; ++m)
      v -= DtD[(size_t)idx[m] * KD + a] * cc[m];
    v = ((amask >> j) & 1u) ? -INFINITY : v;
    if (v > vb) { vb = v; ab = a; }   // j ascending -> keeps smallest atom on tie
  }
  // ----- wave argmax, tie-break: smallest atom index (matches jnp.argmax) -----
  #pragma unroll
  for (int s = 32; s >= 1; s >>= 1) {
    double ov = __shfl_xor(vb, s, 64);
    int    oa = __shfl_xor(ab, s, 64);
    if (ov > vb || (ov == vb && oa < ab)) { vb = ov; ab = oa; }
  }
  idx[K] = ab;
  if ((ab & 63) == lane) amask |= 1u << (ab >> 6);
  // ----- grow Gram -----
  #pragma unroll
  for (int m = 0; m < K; ++m) {
    double gmk = DtD[(size_t)ab * KD + idx[m]];
    G[K][m] = gmk; G[m][K] = gmk;
  }
  G[K][K] = DtD[(size_t)ab * KD + ab];
  c0sel[K] = c0row[ab];
  // ----- y_m = corr0[idx_m] - sum_p G[m][p] * c_prev[p]  (== Dt_sel . r) -----
  double y[K + 1];
  #pragma unroll
  for (int m = 0; m <= K; ++m) {
    double s = c0sel[m];
    #pragma unroll
    for (int pp = 0; pp < K; ++pp) s -= G[m][pp] * cc[pp];
    y[m] = s;
  }
  // ----- solve (K+1)x(K+1) SPD system, unrolled Gaussian elimination -----
  double A[K + 1][K + 1];
  #pragma unroll
  for (int i = 0; i <= K; ++i)
    #pragma unroll
    for (int j2 = 0; j2 <= K; ++j2) A[i][j2] = G[i][j2];
  #pragma unroll
  for (int i = 0; i <= K; ++i) {
    double inv = 1.0 / A[i][i];
    #pragma unroll
    for (int r = i + 1; r <= K; ++r) {
      double f = A[r][i] * inv;
      #pragma unroll
      for (int q = i + 1; q <= K; ++q) A[r][q] -= f * A[i][q];
      y[r] -= f * y[i];
    }
  }
  #pragma unroll
  for (int i = K; i >= 0; --i) {
    double s = y[i];
    #pragma unroll
    for (int q = i + 1; q <= K; ++q) s -= A[i][q] * cc[q];
    cc[i] = s / A[i][i];
  }
}

__global__ __launch_bounds__(256) void k_omp(const double* __restrict__ corr0,
                                             const double* __restrict__ DtD,
                                             float* __restrict__ coefOut,
                                             int* __restrict__ idxWs,
                                             double* __restrict__ cWs,
                                             double* __restrict__ csumWs, int n0) {
  int lane = threadIdx.x & 63;
  int sigRel = blockIdx.x * 4 + (threadIdx.x >> 6);
  int n = n0 + sigRel;
  const double* c0row = corr0 + (size_t)sigRel * KD;
  double c0[8];
  #pragma unroll
  for (int j = 0; j < 8; ++j) c0[j] = c0row[(j << 6) + lane];
  unsigned amask = 0;
  int idx[SP]; double cc[SP]; double G[SP][SP]; double c0sel[SP];
  omp_iter<0>(c0row, DtD, c0, amask, idx, cc, G, c0sel, lane);
  omp_iter<1>(c0row, DtD, c0, amask, idx, cc, G, c0sel, lane);
  omp_iter<2>(c0row, DtD, c0, amask, idx, cc, G, c0sel, lane);
  omp_iter<3>(c0row, DtD, c0, amask, idx, cc, G, c0sel, lane);
  omp_iter<4>(c0row, DtD, c0, amask, idx, cc, G, c0sel, lane);
  if (lane == 0) {
    double cs = 0.0;
    #pragma unroll
    for (int j = 0; j < SP; ++j) {
      double cj = cc[j];
      cj = fmin(fmax(cj, -10000000.0), 10000000.0);   // COEFF_CLAMP
      cs += fabs(cj);
      idxWs[n * SP + j] = idx[j];
      cWs[n * SP + j] = cj;
      coefOut[(size_t)idx[j] * NSIG + n] = (float)cj;
    }
    csumWs[n] = cs;
  }
}

// ---------------- kernel D: z_q + per-block rec-loss partials ----------------
__global__ __launch_bounds__(256) void k_zq(const float* __restrict__ z,
                                            const float* __restrict__ D,
                                            const int* __restrict__ idxWs,
                                            const double* __restrict__ cWs,
                                            float* __restrict__ zqOut,
                                            double* __restrict__ recWs) {
  int t = threadIdx.x;
  size_t flat = (size_t)blockIdx.x * 256 + t;   // indexes z / z_q directly
  int b = (int)(flat >> 16);
  int e = (int)((flat >> 10) & 63);
  int p = (int)(flat & 1023);
  int n = b * 1024 + p;
  double u = 0.0;
  #pragma unroll
  for (int j = 0; j < SP; ++j) {
    int a = idxWs[n * SP + j];
    u += (double)D[e * KD + a] * cWs[n * SP + j];
  }
  float zv = z[flat];
  double d = u - (double)zv;
  double dc = fmin(fmax(d, -1.0), 1.0);
  zqOut[flat] = (float)((double)zv + dc);
  __shared__ double red[256];
  red[t] = d * d;
  __syncthreads();
  #pragma unroll
  for (int s = 128; s >= 1; s >>= 1) {
    if (t < s) red[t] += red[t + s];
    __syncthreads();
  }
  if (t == 0) recWs[blockIdx.x] = red[0];
}

// ---------------- kernel E: deterministic final reduction -> loss ----------------
__global__ __launch_bounds__(256) void k_loss(const double* __restrict__ recWs,
                                              const double* __restrict__ csumWs,
                                              float* __restrict__ lossOut) {
  int t = threadIdx.x;
  double r = 0.0, c = 0.0;
  for (int i = t; i < 8192; i += 256) r += recWs[i];
  for (int i = t; i < NSIG; i += 256) c += csumWs[i];
  __shared__ double red[512];
  red[t] = r; red[256 + t] = c;
  __syncthreads();
  #pragma unroll
  for (int s = 128; s >= 1; s >>= 1) {
    if (t < s) { red[t] += red[t + s]; red[256 + t] += red[256 + t + s]; }
    __syncthreads();
  }
  if (t == 0) {
    double rec = red[0] / (double)(64.0 * 32768.0);
    double cm  = red[256] / (double)(512.0 * 32768.0);
    // loss = rec + 0.25*(1+5/10)*commit + 1e-3*coeff ; commit == rec numerically
    double loss = rec + 0.375 * rec + 0.001 * cm;
    lossOut[0] = (float)loss;
  }
}

extern "C" void kernel_launch(void* const* d_in, const int* in_sizes, int n_in,
                              void* d_out, int out_size, void* d_ws, size_t ws_size,
                              hipStream_t stream) {
  const float* z = (const float*)d_in[0];       // (32,64,32,32)
  const float* D = (const float*)d_in[1];       // (64,512)
  float* out = (float*)d_out;
  float* zqOut   = out;                         // 2097152
  float* lossOut = out + 2097152;               // 1
  float* coefOut = out + 2097153;               // 512*32768

  // workspace carve (all 8B-aligned offsets)
  char* w = (char*)d_ws;
  double* DtD    = (double*)w; w += (size_t)KD * KD * 8;        // 2 MB
  int*    idxWs  = (int*)w;    w += (size_t)NSIG * SP * 4;      // 640 KB
  double* cWs    = (double*)w; w += (size_t)NSIG * SP * 8;      // 1.25 MB
  double* csumWs = (double*)w; w += (size_t)NSIG * 8;           // 256 KB
  double* recWs  = (double*)w; w += (size_t)8192 * 8;           // 64 KB
  double* corr0  = (double*)w;                                  // chunk * 512 * 8
  size_t fixed = (size_t)(w - (char*)d_ws);
  long long avail = (long long)ws_size - (long long)fixed;
  int chunk = NSIG;
  while (chunk > 1024 && (long long)chunk * KD * 8 > avail) chunk >>= 1;

  k_dtd<<<1024, 256, 0, stream>>>(D, DtD);
  k_zero<<<4096, 256, 0, stream>>>(coefOut, (size_t)KD * NSIG);
  for (int n0 = 0; n0 < NSIG; n0 += chunk) {
    int cs = NSIG - n0; if (cs > chunk) cs = chunk;
    k_corr0<<<cs / 16, 256, 0, stream>>>(z, D, corr0, n0);
    k_omp<<<cs / 4, 256, 0, stream>>>(corr0, DtD, coefOut, idxWs, cWs, csumWs, n0);
  }
  k_zq<<<8192, 256, 0, stream>>>(z, D, idxWs, cWs, zqOut, recWs);
  k_loss<<<1, 256, 0, stream>>>(recWs, csumWs, lossOut);
}

// Round 3
// 247.401 us; speedup vs baseline: 1.1568x; 1.1568x over previous
//
#include <hip/hip_runtime.h>
#include <math.h>

#define NSIG 32768
#define KD   512
#define ED   64
#define SP   5

__host__ __device__ constexpr int TRI(int i, int j) {  // i <= j
  return i * SP - i * (i + 1) / 2 + j;
}

// ---------------- kernel A: DtD = Dt @ D + eps*I  (f64) ----------------
__global__ __launch_bounds__(256) void k_dtd(const float* __restrict__ D,
                                             double* __restrict__ DtD) {
  int flat = blockIdx.x * 256 + threadIdx.x;   // 0..262143
  int i = flat >> 9, j = flat & 511;
  double acc = 0.0;
  #pragma unroll
  for (int e = 0; e < ED; ++e)
    acc += (double)D[e * KD + i] * (double)D[e * KD + j];
  if (i == j) acc += 1e-10;
  DtD[flat] = acc;
}

// ---------------- zero the coefficients output region ----------------
__global__ __launch_bounds__(256) void k_zero(float* __restrict__ p, size_t count) {
  size_t i = (size_t)blockIdx.x * 256 + threadIdx.x;
  size_t stride = (size_t)gridDim.x * 256;
  for (; i < count; i += stride) p[i] = 0.0f;
}

// ---------------- kernel B: corr0 = Dt @ Z  (f64 accumulate) ----------------
// tile: 512 atoms x 16 signals per block; thread: 8 atoms x 4 signals
__global__ __launch_bounds__(256) void k_corr0(const float* __restrict__ z,
                                               const float* __restrict__ D,
                                               double* __restrict__ corr0, int n0) {
  int tid = threadIdx.x;
  int g  = tid & 63;        // atom group: atoms g*8 .. g*8+7
  int sg = tid >> 6;        // 0..3 signal subgroup
  int srel = blockIdx.x * 16 + sg * 4;      // chunk-relative signal base
  int n = n0 + srel;
  int b = n >> 10, p = n & 1023;
  const float* zp = z + (size_t)b * 65536 + p;   // + e*1024
  const float* dp = D + g * 8;                   // + e*512
  double acc[4][8];
  #pragma unroll
  for (int s = 0; s < 4; ++s)
    #pragma unroll
    for (int a = 0; a < 8; ++a) acc[s][a] = 0.0;
  for (int e = 0; e < ED; ++e) {
    const float4 zv = *(const float4*)(zp + (size_t)e * 1024);
    const float4 d0 = *(const float4*)(dp + (size_t)e * KD);
    const float4 d1 = *(const float4*)(dp + (size_t)e * KD + 4);
    double dz[4] = {(double)zv.x, (double)zv.y, (double)zv.z, (double)zv.w};
    double dd[8] = {(double)d0.x, (double)d0.y, (double)d0.z, (double)d0.w,
                    (double)d1.x, (double)d1.y, (double)d1.z, (double)d1.w};
    #pragma unroll
    for (int s = 0; s < 4; ++s)
      #pragma unroll
      for (int a = 0; a < 8; ++a) acc[s][a] += dz[s] * dd[a];
  }
  #pragma unroll
  for (int s = 0; s < 4; ++s) {
    double* o = corr0 + (size_t)(srel + s) * KD + g * 8;
    #pragma unroll
    for (int a = 0; a < 8; ++a) o[a] = acc[s][a];
  }
}

// ---------------- kernel C: per-signal OMP (32 lanes per signal) ----------------
// Maintains Ginv (15-entry upper triangle) via Schur-complement rank-1 update:
//   u = Ginv*b ; s = d - b.u ; r = 1/s
//   Ginv' = [[Ginv + r u u^T, -r u],[-r u^T, r]]
// Reference algebra: cc_new = Ginv*c0sel - pad(cc_old)   (y = c0sel - G*pad(cc_old))
template <int K>
__device__ __forceinline__ void omp_iter(const double* __restrict__ c0row,
                                         const double* __restrict__ DtD,
                                         const double (&c0)[16], unsigned& amask,
                                         int (&idx)[SP], double (&cc)[SP],
                                         double (&tri)[15], double (&c0sel)[SP],
                                         int li) {
  // ----- masked corr scan over this lane's 16 atoms -----
  double vb = -INFINITY;
  int ab = 0x7FFFFFFF;
  #pragma unroll
  for (int j = 0; j < 16; ++j) {
    int a = (j << 5) + li;
    double v = c0[j];
    #pragma unroll
    for (int m = 0; m < K; ++m)
      v -= DtD[(size_t)idx[m] * KD + a] * cc[m];
    v = ((amask >> j) & 1u) ? -INFINITY : v;
    if (v > vb) { vb = v; ab = a; }   // j ascending -> smallest atom on lane-local tie
  }
  // ----- 32-lane group argmax, tie-break: smallest atom (matches jnp.argmax) -----
  #pragma unroll
  for (int s = 16; s >= 1; s >>= 1) {
    double ov = __shfl_xor(vb, s, 64);
    int    oa = __shfl_xor(ab, s, 64);
    if (ov > vb || (ov == vb && oa < ab)) { vb = ov; ab = oa; }
  }
  idx[K] = ab;
  if ((ab & 31) == li) amask |= 1u << (ab >> 5);
  c0sel[K] = c0row[ab];
  // ----- gather new Gram row -----
  const double* drow = DtD + (size_t)ab * KD;
  double b[SP], u[SP];
  #pragma unroll
  for (int m = 0; m < K; ++m) b[m] = drow[idx[m]];
  double sch = drow[ab];
  #pragma unroll
  for (int i = 0; i < K; ++i) {
    double ui = 0.0;
    #pragma unroll
    for (int m = 0; m < K; ++m) {
      int lo = i < m ? i : m, hi = i < m ? m : i;
      ui += tri[lo * SP - lo * (lo + 1) / 2 + hi] * b[m];
    }
    u[i] = ui;
    sch -= b[i] * ui;
  }
  double r = 1.0 / sch;
  #pragma unroll
  for (int i = 0; i < K; ++i) {
    #pragma unroll
    for (int j = i; j < K; ++j) tri[i * SP - i * (i + 1) / 2 + j] += r * u[i] * u[j];
    tri[i * SP - i * (i + 1) / 2 + K] = -r * u[i];
  }
  tri[K * SP - K * (K + 1) / 2 + K] = r;
  // ----- h = Ginv_new * c0sel ; cc = h - pad(cc_old) -----
  double h[SP];
  #pragma unroll
  for (int i = 0; i <= K; ++i) {
    double s = 0.0;
    #pragma unroll
    for (int j = 0; j <= K; ++j) {
      int lo = i < j ? i : j, hi = i < j ? j : i;
      s += tri[lo * SP - lo * (lo + 1) / 2 + hi] * c0sel[j];
    }
    h[i] = s;
  }
  #pragma unroll
  for (int i = 0; i < K; ++i) cc[i] = h[i] - cc[i];
  cc[K] = h[K];
}

__global__ __launch_bounds__(256) void k_omp(const double* __restrict__ corr0,
                                             const double* __restrict__ DtD,
                                             float* __restrict__ coefOut,
                                             int* __restrict__ idxWs,
                                             double* __restrict__ cWs,
                                             double* __restrict__ csumWs, int n0) {
  int tid = threadIdx.x;
  int lane = tid & 63;
  int li = lane & 31;               // lane within signal group
  int g  = lane >> 5;               // signal within wave (0..1)
  int sigRel = blockIdx.x * 8 + (tid >> 6) * 2 + g;
  int n = n0 + sigRel;
  const double* c0row = corr0 + (size_t)sigRel * KD;
  double c0[16];
  #pragma unroll
  for (int j = 0; j < 16; ++j) c0[j] = c0row[(j << 5) + li];
  unsigned amask = 0;
  int idx[SP]; double cc[SP]; double tri[15]; double c0sel[SP];
  omp_iter<0>(c0row, DtD, c0, amask, idx, cc, tri, c0sel, li);
  omp_iter<1>(c0row, DtD, c0, amask, idx, cc, tri, c0sel, li);
  omp_iter<2>(c0row, DtD, c0, amask, idx, cc, tri, c0sel, li);
  omp_iter<3>(c0row, DtD, c0, amask, idx, cc, tri, c0sel, li);
  omp_iter<4>(c0row, DtD, c0, amask, idx, cc, tri, c0sel, li);
  if (li == 0) {
    double cs = 0.0;
    #pragma unroll
    for (int j = 0; j < SP; ++j) {
      double cj = cc[j];
      cj = fmin(fmax(cj, -10000000.0), 10000000.0);   // COEFF_CLAMP
      cs += fabs(cj);
      idxWs[n * SP + j] = idx[j];
      cWs[n * SP + j] = cj;
      coefOut[(size_t)idx[j] * NSIG + n] = (float)cj;
    }
    csumWs[n] = cs;
  }
}

// ---------------- kernel D: z_q + per-block rec-loss partials ----------------
__global__ __launch_bounds__(256) void k_zq(const float* __restrict__ z,
                                            const float* __restrict__ D,
                                            const int* __restrict__ idxWs,
                                            const double* __restrict__ cWs,
                                            float* __restrict__ zqOut,
                                            double* __restrict__ recWs) {
  int t = threadIdx.x;
  size_t flat = (size_t)blockIdx.x * 256 + t;   // indexes z / z_q directly
  int b = (int)(flat >> 16);
  int e = (int)((flat >> 10) & 63);
  int p = (int)(flat & 1023);
  int n = b * 1024 + p;
  double u = 0.0;
  #pragma unroll
  for (int j = 0; j < SP; ++j) {
    int a = idxWs[n * SP + j];
    u += (double)D[e * KD + a] * cWs[n * SP + j];
  }
  float zv = z[flat];
  double d = u - (double)zv;
  double dc = fmin(fmax(d, -1.0), 1.0);
  zqOut[flat] = (float)((double)zv + dc);
  __shared__ double red[256];
  red[t] = d * d;
  __syncthreads();
  #pragma unroll
  for (int s = 128; s >= 1; s >>= 1) {
    if (t < s) red[t] += red[t + s];
    __syncthreads();
  }
  if (t == 0) recWs[blockIdx.x] = red[0];
}

// ---------------- kernel E: deterministic final reduction -> loss ----------------
__global__ __launch_bounds__(256) void k_loss(const double* __restrict__ recWs,
                                              const double* __restrict__ csumWs,
                                              float* __restrict__ lossOut) {
  int t = threadIdx.x;
  double r = 0.0, c = 0.0;
  for (int i = t; i < 8192; i += 256) r += recWs[i];
  for (int i = t; i < NSIG; i += 256) c += csumWs[i];
  __shared__ double red[512];
  red[t] = r; red[256 + t] = c;
  __syncthreads();
  #pragma unroll
  for (int s = 128; s >= 1; s >>= 1) {
    if (t < s) { red[t] += red[t + s]; red[256 + t] += red[256 + t + s]; }
    __syncthreads();
  }
  if (t == 0) {
    double rec = red[0] / (double)(64.0 * 32768.0);
    double cm  = red[256] / (double)(512.0 * 32768.0);
    // loss = rec + 0.25*(1+5/10)*commit + 1e-3*coeff ; commit == rec numerically
    double loss = rec + 0.375 * rec + 0.001 * cm;
    lossOut[0] = (float)loss;
  }
}

extern "C" void kernel_launch(void* const* d_in, const int* in_sizes, int n_in,
                              void* d_out, int out_size, void* d_ws, size_t ws_size,
                              hipStream_t stream) {
  const float* z = (const float*)d_in[0];       // (32,64,32,32)
  const float* D = (const float*)d_in[1];       // (64,512)
  float* out = (float*)d_out;
  float* zqOut   = out;                         // 2097152
  float* lossOut = out + 2097152;               // 1
  float* coefOut = out + 2097153;               // 512*32768

  // workspace carve (all 8B-aligned offsets)
  char* w = (char*)d_ws;
  double* DtD    = (double*)w; w += (size_t)KD * KD * 8;        // 2 MB
  int*    idxWs  = (int*)w;    w += (size_t)NSIG * SP * 4;      // 640 KB
  double* cWs    = (double*)w; w += (size_t)NSIG * SP * 8;      // 1.25 MB
  double* csumWs = (double*)w; w += (size_t)NSIG * 8;           // 256 KB
  double* recWs  = (double*)w; w += (size_t)8192 * 8;           // 64 KB
  double* corr0  = (double*)w;                                  // chunk * 512 * 8
  size_t fixed = (size_t)(w - (char*)d_ws);
  long long avail = (long long)ws_size - (long long)fixed;
  int chunk = NSIG;
  while (chunk > 1024 && (long long)chunk * KD * 8 > avail) chunk >>= 1;

  k_dtd<<<1024, 256, 0, stream>>>(D, DtD);
  k_zero<<<4096, 256, 0, stream>>>(coefOut, (size_t)KD * NSIG);
  for (int n0 = 0; n0 < NSIG; n0 += chunk) {
    int cs = NSIG - n0; if (cs > chunk) cs = chunk;
    k_corr0<<<cs / 16, 256, 0, stream>>>(z, D, corr0, n0);
    k_omp<<<cs / 8, 256, 0, stream>>>(corr0, DtD, coefOut, idxWs, cWs, csumWs, n0);
  }
  k_zq<<<8192, 256, 0, stream>>>(z, D, idxWs, cWs, zqOut, recWs);
  k_loss<<<1, 256, 0, stream>>>(recWs, csumWs, lossOut);
}

// Round 4
// 233.827 us; speedup vs baseline: 1.2240x; 1.0581x over previous
//
#include <hip/hip_runtime.h>
#include <math.h>

#define NSIG 32768
#define KD   512
#define ED   64
#define SP   5

// ---------------- kernel A: DtD = Dt @ D + eps*I  (f64) ----------------
__global__ __launch_bounds__(256) void k_dtd(const float* __restrict__ D,
                                             double* __restrict__ DtD) {
  int flat = blockIdx.x * 256 + threadIdx.x;   // 0..262143
  int i = flat >> 9, j = flat & 511;
  double acc = 0.0;
  #pragma unroll
  for (int e = 0; e < ED; ++e)
    acc += (double)D[e * KD + i] * (double)D[e * KD + j];
  if (i == j) acc += 1e-10;
  DtD[flat] = acc;
}

// ---------------- zero the coefficients output region ----------------
__global__ __launch_bounds__(256) void k_zero(float* __restrict__ p, size_t count) {
  size_t i = (size_t)blockIdx.x * 256 + threadIdx.x;
  size_t stride = (size_t)gridDim.x * 256;
  for (; i < count; i += stride) p[i] = 0.0f;
}

// ---------------- fused kernel: corr0 compute + per-signal OMP ----------------
// Lane->atom ownership (pair mapping): lane li owns atoms { 64*j2 + 2*li + bit },
// j2=0..7, bit=0..1; c0[2*j2+bit] is the f64 running correlation of that atom.
// Ginv (15-entry triangle) maintained via Schur rank-1 update (1 rcp per iter).
// cc_new = Ginv*c0sel - pad(cc_old)  (reference algebra: y = c0sel - G*pad(cc_old))
template <int K>
__device__ __forceinline__ void omp_iter(const double* __restrict__ DtD,
                                         const double (&c0)[16], unsigned& amask,
                                         int (&idx)[SP], double (&cc)[SP],
                                         double (&tri)[15], double (&c0sel)[SP],
                                         int li) {
  // ----- masked corr scan over this lane's 16 atoms (8 pairs, 16B loads) -----
  double vb = -INFINITY;
  int ab = 0x7FFFFFFF;
  #pragma unroll
  for (int j2 = 0; j2 < 8; ++j2) {
    int a0 = (j2 << 6) + (li << 1);
    double v0 = c0[2 * j2], v1 = c0[2 * j2 + 1];
    #pragma unroll
    for (int m = 0; m < K; ++m) {
      double2 g2 = *(const double2*)(DtD + (size_t)idx[m] * KD + a0);
      v0 -= g2.x * cc[m];
      v1 -= g2.y * cc[m];
    }
    v0 = ((amask >> (2 * j2)) & 1u) ? -INFINITY : v0;
    v1 = ((amask >> (2 * j2 + 1)) & 1u) ? -INFINITY : v1;
    if (v0 > vb) { vb = v0; ab = a0; }        // ascending atoms per lane:
    if (v1 > vb) { vb = v1; ab = a0 + 1; }    // lane-local ties keep smallest
  }
  // ----- 32-lane group argmax, tie-break: smallest atom (matches jnp.argmax) -----
  #pragma unroll
  for (int s = 16; s >= 1; s >>= 1) {
    double ov = __shfl_xor(vb, s, 64);
    int    oa = __shfl_xor(ab, s, 64);
    if (ov > vb || (ov == vb && oa < ab)) { vb = ov; ab = oa; }
  }
  idx[K] = ab;
  if (((ab >> 1) & 31) == li) amask |= 1u << ((((ab >> 6) << 1)) | (ab & 1));
  // ----- gather new Gram row entries (symmetric: also used to rebuild c0sel) -----
  const double* drow = DtD + (size_t)ab * KD;
  double bb[SP], u[SP];
  #pragma unroll
  for (int m = 0; m < K; ++m) bb[m] = drow[idx[m]];
  // c0sel[K] = corr0[ab] = vb + sum_m DtD[ab,idx_m]*cc_m  (symmetry: = bb[m])
  {
    double csel = vb;
    #pragma unroll
    for (int m = 0; m < K; ++m) csel += bb[m] * cc[m];
    c0sel[K] = csel;
  }
  // ----- Schur rank-1 update of Ginv triangle -----
  double sch = drow[ab];
  #pragma unroll
  for (int i = 0; i < K; ++i) {
    double ui = 0.0;
    #pragma unroll
    for (int m = 0; m < K; ++m) {
      int lo = i < m ? i : m, hi = i < m ? m : i;
      ui += tri[lo * SP - lo * (lo + 1) / 2 + hi] * bb[m];
    }
    u[i] = ui;
    sch -= bb[i] * ui;
  }
  double r = 1.0 / sch;
  #pragma unroll
  for (int i = 0; i < K; ++i) {
    #pragma unroll
    for (int j = i; j < K; ++j) tri[i * SP - i * (i + 1) / 2 + j] += r * u[i] * u[j];
    tri[i * SP - i * (i + 1) / 2 + K] = -r * u[i];
  }
  tri[K * SP - K * (K + 1) / 2 + K] = r;
  // ----- h = Ginv_new * c0sel ; cc = h - pad(cc_old) -----
  double h[SP];
  #pragma unroll
  for (int i = 0; i <= K; ++i) {
    double s = 0.0;
    #pragma unroll
    for (int j = 0; j <= K; ++j) {
      int lo = i < j ? i : j, hi = i < j ? j : i;
      s += tri[lo * SP - lo * (lo + 1) / 2 + hi] * c0sel[j];
    }
    h[i] = s;
  }
  #pragma unroll
  for (int i = 0; i < K; ++i) cc[i] = h[i] - cc[i];
  cc[K] = h[K];
}

__global__ __launch_bounds__(256) void k_fused(const float* __restrict__ z,
                                               const float* __restrict__ D,
                                               const double* __restrict__ DtD,
                                               float* __restrict__ coefOut,
                                               int* __restrict__ idxWs,
                                               double* __restrict__ cWs,
                                               double* __restrict__ csumWs) {
  __shared__ float Dlds[16 * 512];   // 32 KB: one 16-row tile of D
  __shared__ float zbuf[64 * 8];     // 2 KB: [e][sig] for the block's 8 signals
  int tid = threadIdx.x;
  int li = tid & 31;
  int mysig = ((tid >> 6) << 1) | ((tid >> 5) & 1);   // 0..7
  int n = blockIdx.x * 8 + mysig;
  int b = n >> 10, p0 = (blockIdx.x * 8) & 1023;
  // ---- stage z for the block's 8 signals: zbuf[e*8+sig] = z[b, e, p0+sig] ----
  {
    const float* zb = z + (size_t)b * 65536 + p0;
    #pragma unroll
    for (int k2 = 0; k2 < 2; ++k2) {
      int f = tid + 256 * k2;
      zbuf[f] = zb[(f >> 3) * 1024 + (f & 7)];
    }
  }
  // ---- fused corr0 compute: c0[j] = sum_e z_n[e] * D[e, atom(j)] (f64) ----
  double c0[16];
  #pragma unroll
  for (int j = 0; j < 16; ++j) c0[j] = 0.0;
  for (int t4 = 0; t4 < 4; ++t4) {
    __syncthreads();   // protect Dlds before overwrite (no-op cost on t4=0)
    {
      const float4* src = (const float4*)(D + t4 * 16 * 512);
      float4* dst = (float4*)Dlds;
      #pragma unroll
      for (int i = 0; i < 8; ++i) dst[tid + 256 * i] = src[tid + 256 * i];
    }
    __syncthreads();
    #pragma unroll 4
    for (int e = 0; e < 16; ++e) {
      double zv = (double)zbuf[(t4 * 16 + e) * 8 + mysig];
      const float* drow = Dlds + e * 512;
      #pragma unroll
      for (int j2 = 0; j2 < 8; ++j2) {
        float2 dv = *(const float2*)(drow + (j2 << 6) + (li << 1));
        c0[2 * j2]     += zv * (double)dv.x;
        c0[2 * j2 + 1] += zv * (double)dv.y;
      }
    }
  }
  // ---- OMP iterations ----
  unsigned amask = 0;
  int idx[SP]; double cc[SP]; double tri[15]; double c0sel[SP];
  omp_iter<0>(DtD, c0, amask, idx, cc, tri, c0sel, li);
  omp_iter<1>(DtD, c0, amask, idx, cc, tri, c0sel, li);
  omp_iter<2>(DtD, c0, amask, idx, cc, tri, c0sel, li);
  omp_iter<3>(DtD, c0, amask, idx, cc, tri, c0sel, li);
  omp_iter<4>(DtD, c0, amask, idx, cc, tri, c0sel, li);
  if (li == 0) {
    double cs = 0.0;
    #pragma unroll
    for (int j = 0; j < SP; ++j) {
      double cj = cc[j];
      cj = fmin(fmax(cj, -10000000.0), 10000000.0);   // COEFF_CLAMP
      cs += fabs(cj);
      idxWs[n * SP + j] = idx[j];
      cWs[n * SP + j] = cj;
      coefOut[(size_t)idx[j] * NSIG + n] = (float)cj;
    }
    csumWs[n] = cs;
  }
}

// ---------------- kernel D: z_q + per-block rec-loss partials ----------------
__global__ __launch_bounds__(256) void k_zq(const float* __restrict__ z,
                                            const float* __restrict__ D,
                                            const int* __restrict__ idxWs,
                                            const double* __restrict__ cWs,
                                            float* __restrict__ zqOut,
                                            double* __restrict__ recWs) {
  int t = threadIdx.x;
  size_t flat = (size_t)blockIdx.x * 256 + t;   // indexes z / z_q directly
  int b = (int)(flat >> 16);
  int e = (int)((flat >> 10) & 63);
  int p = (int)(flat & 1023);
  int n = b * 1024 + p;
  double u = 0.0;
  #pragma unroll
  for (int j = 0; j < SP; ++j) {
    int a = idxWs[n * SP + j];
    u += (double)D[e * KD + a] * cWs[n * SP + j];
  }
  float zv = z[flat];
  double d = u - (double)zv;
  double dc = fmin(fmax(d, -1.0), 1.0);
  zqOut[flat] = (float)((double)zv + dc);
  __shared__ double red[256];
  red[t] = d * d;
  __syncthreads();
  #pragma unroll
  for (int s = 128; s >= 1; s >>= 1) {
    if (t < s) red[t] += red[t + s];
    __syncthreads();
  }
  if (t == 0) recWs[blockIdx.x] = red[0];
}

// ---------------- kernel E: deterministic final reduction -> loss ----------------
__global__ __launch_bounds__(256) void k_loss(const double* __restrict__ recWs,
                                              const double* __restrict__ csumWs,
                                              float* __restrict__ lossOut) {
  int t = threadIdx.x;
  double r = 0.0, c = 0.0;
  for (int i = t; i < 8192; i += 256) r += recWs[i];
  for (int i = t; i < NSIG; i += 256) c += csumWs[i];
  __shared__ double red[512];
  red[t] = r; red[256 + t] = c;
  __syncthreads();
  #pragma unroll
  for (int s = 128; s >= 1; s >>= 1) {
    if (t < s) { red[t] += red[t + s]; red[256 + t] += red[256 + t + s]; }
    __syncthreads();
  }
  if (t == 0) {
    double rec = red[0] / (double)(64.0 * 32768.0);
    double cm  = red[256] / (double)(512.0 * 32768.0);
    // loss = rec + 0.25*(1+5/10)*commit + 1e-3*coeff ; commit == rec numerically
    double loss = rec + 0.375 * rec + 0.001 * cm;
    lossOut[0] = (float)loss;
  }
}

extern "C" void kernel_launch(void* const* d_in, const int* in_sizes, int n_in,
                              void* d_out, int out_size, void* d_ws, size_t ws_size,
                              hipStream_t stream) {
  const float* z = (const float*)d_in[0];       // (32,64,32,32)
  const float* D = (const float*)d_in[1];       // (64,512)
  float* out = (float*)d_out;
  float* zqOut   = out;                         // 2097152
  float* lossOut = out + 2097152;               // 1
  float* coefOut = out + 2097153;               // 512*32768

  // workspace carve (all 8B-aligned offsets)
  char* w = (char*)d_ws;
  double* DtD    = (double*)w; w += (size_t)KD * KD * 8;        // 2 MB
  int*    idxWs  = (int*)w;    w += (size_t)NSIG * SP * 4;      // 640 KB
  double* cWs    = (double*)w; w += (size_t)NSIG * SP * 8;      // 1.25 MB
  double* csumWs = (double*)w; w += (size_t)NSIG * 8;           // 256 KB
  double* recWs  = (double*)w; w += (size_t)8192 * 8;           // 64 KB

  k_dtd<<<1024, 256, 0, stream>>>(D, DtD);
  k_zero<<<4096, 256, 0, stream>>>(coefOut, (size_t)KD * NSIG);
  k_fused<<<NSIG / 8, 256, 0, stream>>>(z, D, DtD, coefOut, idxWs, cWs, csumWs);
  k_zq<<<8192, 256, 0, stream>>>(z, D, idxWs, cWs, zqOut, recWs);
  k_loss<<<1, 256, 0, stream>>>(recWs, csumWs, lossOut);
}